// Round 11
// baseline (315.915 us; speedup 1.0000x reference)
//
#include <hip/hip_runtime.h>
#include <hip/hip_bf16.h>
#include <stdint.h>

#define VOCAB 50257
#define WD 300
#define KP1 320              // word dim padded to mult of 32
#define MP 50432             // vocab rows padded: 394*128

using bf16 = __hip_bfloat16;
typedef __attribute__((ext_vector_type(4))) float f32x4;
typedef __attribute__((ext_vector_type(8))) short bf16x8;

// async global->LDS, 16B per lane; LDS dest = wave-uniform base + lane*16
__device__ __forceinline__ void async_load16(const void* g, void* l) {
    __builtin_amdgcn_global_load_lds(
        (const __attribute__((address_space(1))) uint32_t*)(uintptr_t)g,
        (__attribute__((address_space(3))) uint32_t*)l, 16, 0, 0);
}

// ---------- prep: w1t = W1^T bf16 [256x320]; w2t = W2^T bf16 [256x512];
//                  w2b = W2 cast bf16 [512x256]; b4 = b2@(A+B)+b2; zbuf zeros(256)
__global__ void prep_w(const float* __restrict__ W1, const float* __restrict__ W2,
                       const float* __restrict__ b2,
                       bf16* __restrict__ w1t, bf16* __restrict__ w2t,
                       bf16* __restrict__ w2b, float* __restrict__ b4,
                       float* __restrict__ zbuf) {
    if (blockIdx.x == 1344) {           // bias block: b4 = b2@(A+B) + b2
        __shared__ float b2s[256];
        int n = threadIdx.x;
        b2s[n] = b2[n];
        zbuf[n] = 0.0f;
        __syncthreads();
        float acc = b2s[n];
        #pragma unroll 8
        for (int k = 0; k < 256; ++k)
            acc += b2s[k] * (W2[k * 256 + n] + W2[(k + 256) * 256 + n]);
        b4[n] = acc;
        return;
    }
    int idx = blockIdx.x * 256 + threadIdx.x;
    if (idx < 256 * KP1) {                              // w1t
        int n = idx / KP1;
        int k = idx - n * KP1;
        w1t[idx] = __float2bfloat16(k < WD ? W1[k * 256 + n] : 0.0f);
    } else if (idx < 256 * KP1 + 131072) {              // w2t
        int j = idx - 256 * KP1;
        int n = j >> 9, k = j & 511;
        w2t[j] = __float2bfloat16(W2[k * 256 + n]);
    } else {                                            // w2b: plain cast
        int j = idx - 256 * KP1 - 131072;
        w2b[j] = __float2bfloat16(W2[j]);
    }
}

// ---------- tile_gemm for combo: 128-row x 256-col, 8 waves ------------------
// AMODE 0: A bf16, row stride As; 3-stage PIPE.  AMODE 2: A fp32 emb; 2-barrier.
template <int AMODE, bool OUT_F32>
__device__ __forceinline__ void tile_gemm(
    char* smem, const void* Av, const bf16* BT, int Bstr, const float* bias,
    void* C, int Cs, int coff, int K, int As, int m0, const float* zbuf)
{
    constexpr int ASZ = (AMODE == 2) ? 16384 : 8192;
    constexpr int BSZ = 16384, STAGE = ASZ + BSZ;

    const int t = threadIdx.x, w = t >> 6, lane = t & 63;
    const int rg = w >> 2, cgr = w & 3, mi = lane & 15, q = lane >> 4;
    const bf16* Ab = (const bf16*)Av;

    auto stage = [&](int ke, int buf) {
        char* Asm = smem + buf * STAGE;
        char* Bsm = Asm + ASZ;
        if constexpr (AMODE == 2) {
            const float* A32 = (const float*)Av;
            #pragma unroll
            for (int i = 0; i < 2; ++i) {
                int s = i * 512 + t;
                int row = s >> 3;
                int kcd = (s & 7) ^ (row & 7);
                int k = ke + kcd * 4;
                int grow = m0 + row; if (grow >= VOCAB) grow = VOCAB - 1;
                const float* g = (k <= 296) ? (A32 + (size_t)grow * WD + k) : zbuf;
                async_load16(g, Asm + i * 8192 + w * 1024);
            }
        } else {
            int row = t >> 2;
            int kcd = (t & 3) ^ ((row >> 2) & 3);
            async_load16(Ab + (size_t)(m0 + row) * As + ke + kcd * 8, Asm + w * 1024);
        }
        #pragma unroll
        for (int i = 0; i < 2; ++i) {
            int s = i * 512 + t;
            int col = s >> 2;
            int kcd = (s & 3) ^ ((col >> 2) & 3);
            async_load16(BT + (size_t)col * Bstr + ke + kcd * 8,
                         Bsm + i * 8192 + w * 1024);
        }
    };

    f32x4 acc[4][4] = {};

    auto compute = [&](int buf) {
        const char* Asm = smem + buf * STAGE;
        const bf16* Bs16 = (const bf16*)(Asm + ASZ);
        bf16x8 af[4], bfr[4];
        if constexpr (AMODE == 2) {
            const float* As32 = (const float*)Asm;
            #pragma unroll
            for (int r = 0; r < 4; ++r) {
                int row = rg * 64 + r * 16 + mi;
                int sl = row * 8 + ((2 * q) ^ (row & 7));
                f32x4 lo = *(const f32x4*)(As32 + sl * 4);
                f32x4 hi = *(const f32x4*)(As32 + (sl ^ 1) * 4);
                union { bf16x8 v; bf16 hh[8]; } u;
                #pragma unroll
                for (int j = 0; j < 4; ++j) u.hh[j] = __float2bfloat16(lo[j]);
                #pragma unroll
                for (int j = 0; j < 4; ++j) u.hh[4 + j] = __float2bfloat16(hi[j]);
                af[r] = u.v;
            }
        } else {
            const bf16* As16 = (const bf16*)Asm;
            #pragma unroll
            for (int r = 0; r < 4; ++r) {
                int row = rg * 64 + r * 16 + mi;
                int slot = row * 4 + (q ^ ((row >> 2) & 3));
                af[r] = *(const bf16x8*)(As16 + slot * 8);
            }
        }
        #pragma unroll
        for (int c = 0; c < 4; ++c) {
            int col = cgr * 64 + c * 16 + mi;
            int slot = col * 4 + (q ^ ((col >> 2) & 3));
            bfr[c] = *(const bf16x8*)(Bs16 + slot * 8);
        }
        #pragma unroll
        for (int r = 0; r < 4; ++r)
            #pragma unroll
            for (int c = 0; c < 4; ++c)
                acc[r][c] = __builtin_amdgcn_mfma_f32_16x16x32_bf16(af[r], bfr[c], acc[r][c], 0, 0, 0);
    };

    const int S = K >> 5;
    if constexpr (AMODE == 2) {
        for (int k0 = 0; k0 < S; ++k0) {
            stage(k0 * 32, 0);
            __syncthreads();
            compute(0);
            __syncthreads();
        }
    } else {
        stage(0, 0);
        if (S > 1) stage(32, 1);
        for (int k0 = 0; k0 < S; ++k0) {
            if (k0 + 1 < S)
                asm volatile("s_waitcnt vmcnt(3)\n\ts_barrier" ::: "memory");
            else
                asm volatile("s_waitcnt vmcnt(0)\n\ts_barrier" ::: "memory");
            if (k0 + 2 < S) stage((k0 + 2) * 32, (k0 + 2) % 3);
            compute(k0 % 3);
        }
    }

    #pragma unroll
    for (int r = 0; r < 4; ++r) {
        int rowb = m0 + rg * 64 + r * 16 + q * 4;
        #pragma unroll
        for (int c = 0; c < 4; ++c) {
            int col = cgr * 64 + c * 16 + mi;
            float bv = bias[col];
            #pragma unroll
            for (int i = 0; i < 4; ++i) {
                float v = acc[r][c][i] + bv;
                size_t o = (size_t)(rowb + i) * Cs + coff + col;
                if (OUT_F32) ((float*)C)[o] = v;
                else         ((bf16*)C)[o] = __float2bfloat16(v);
            }
        }
    }
}

// ---------- D2: W4T (blocks 0..7) || proj (blocks 8..401) --------------------
__global__ __launch_bounds__(512)
void combo(const float* __restrict__ emb, const bf16* __restrict__ w1t,
           const float* __restrict__ b1, const bf16* __restrict__ w2t,
           const bf16* __restrict__ w2b, bf16* __restrict__ w4t,
           bf16* __restrict__ proj, const float* __restrict__ zbuf) {
    __shared__ char smem[73728];
    int blk = blockIdx.x;
    if (blk < 8) {
        int j = blk >> 1, s = blk & 1;
        tile_gemm<0, false>(smem, w2t + 256 * (j >> 1), w2b + 65536 * (j & 1),
                            256, zbuf, w4t, 1024, 256 * j, 256, 512, s * 128, nullptr);
    } else {
        tile_gemm<2, false>(smem, emb, w1t, KP1, b1,
                            proj, 256, 0, KP1, WD, (blk - 8) * 128, zbuf);
    }
}

// ---------- D3: mainK — gather + levels 0-3 per block ------------------------
// Phase A: h-tile [128x256] = concat4(proj[ids4]) @ W4 + b4 (verified PIPE),
// epilogue to LDS Ht (overlays freed pipeline bufs; LDS stays 72KB, 2 blk/CU).
// Phase B: t1 rows [32b,32b+32) = view(Ht,[32x1024]) @ W4 + b4 — B-frags
// loaded global->VGPR w/ 2-deep prefetch, NO barriers (TLP hides L2 latency).
__global__ __launch_bounds__(512, 4)
void mainK(const bf16* __restrict__ proj, const int* __restrict__ ids,
           const bf16* __restrict__ w4t, const float* __restrict__ b4,
           bf16* __restrict__ t1) {
    constexpr int ASZ = 8192, STAGE = ASZ + 16384;
    __shared__ char smem[3 * STAGE];          // 72 KB
    bf16* Ht = (bf16*)smem;                   // 64 KB overlay (after phase A)

    const int t = threadIdx.x, w = t >> 6, lane = t & 63;
    const int rg = w >> 2, cgr = w & 3, mi = lane & 15, q = lane >> 4;
    const int m0 = blockIdx.x * 128;

    const int4 idq = ((const int4*)ids)[m0 + (t >> 2)];

    auto stage = [&](int ke, int buf) {
        char* Asm = smem + buf * STAGE;
        char* Bsm = Asm + ASZ;
        int row = t >> 2;
        int kcd = (t & 3) ^ ((row >> 2) & 3);
        int sel = ke >> 8;
        int id = (sel & 2) ? ((sel & 1) ? idq.w : idq.z)
                           : ((sel & 1) ? idq.y : idq.x);
        async_load16(proj + (size_t)id * 256 + (ke & 255) + kcd * 8, Asm + w * 1024);
        #pragma unroll
        for (int i = 0; i < 2; ++i) {
            int s = i * 512 + t;
            int col = s >> 2;
            int kcd2 = (s & 3) ^ ((col >> 2) & 3);
            async_load16(w4t + (size_t)col * 1024 + ke + kcd2 * 8,
                         Bsm + i * 8192 + w * 1024);
        }
    };

    f32x4 acc[4][4] = {};
    stage(0, 0); stage(32, 1);
    for (int k0i = 0; k0i < 32; ++k0i) {
        if (k0i + 1 < 32)
            asm volatile("s_waitcnt vmcnt(3)\n\ts_barrier" ::: "memory");
        else
            asm volatile("s_waitcnt vmcnt(0)\n\ts_barrier" ::: "memory");
        if (k0i + 2 < 32) stage((k0i + 2) * 32, (k0i + 2) % 3);
        const bf16* As16 = (const bf16*)(smem + (k0i % 3) * STAGE);
        const bf16* Bs16 = (const bf16*)(smem + (k0i % 3) * STAGE + ASZ);
        bf16x8 af[4], bfr[4];
        #pragma unroll
        for (int r = 0; r < 4; ++r) {
            int row = rg * 64 + r * 16 + mi;
            int slot = row * 4 + (q ^ ((row >> 2) & 3));
            af[r] = *(const bf16x8*)(As16 + slot * 8);
        }
        #pragma unroll
        for (int c = 0; c < 4; ++c) {
            int col = cgr * 64 + c * 16 + mi;
            int slot = col * 4 + (q ^ ((col >> 2) & 3));
            bfr[c] = *(const bf16x8*)(Bs16 + slot * 8);
        }
        #pragma unroll
        for (int r = 0; r < 4; ++r)
            #pragma unroll
            for (int c = 0; c < 4; ++c)
                acc[r][c] = __builtin_amdgcn_mfma_f32_16x16x32_bf16(af[r], bfr[c], acc[r][c], 0, 0, 0);
    }
    __syncthreads();          // all waves done with stage buffers

    // epilogue -> Ht: slot(row,col) = (row*32 + ((col>>3) ^ (row&31)))*8 + (col&7)
    #pragma unroll
    for (int r = 0; r < 4; ++r) {
        int rowb = rg * 64 + r * 16 + q * 4;
        #pragma unroll
        for (int c = 0; c < 4; ++c) {
            int col = cgr * 64 + c * 16 + mi;
            float bv = b4[col];
            int chunk = col >> 3;
            #pragma unroll
            for (int i = 0; i < 4; ++i) {
                int row = rowb + i;
                Ht[(row * 32 + (chunk ^ (row & 31))) * 8 + (col & 7)] =
                    __float2bfloat16(acc[r][c][i] + bv);
            }
        }
    }
    __syncthreads();

    // phase B: 32 t1-rows, register-pipelined B, no barriers
    f32x4 acc2[4] = {};
    bf16x8 b0[4], b1[4];
    auto loadB = [&](int k0, bf16x8 (&dst)[4]) {
        #pragma unroll
        for (int c = 0; c < 4; ++c) {
            int col = cgr * 64 + c * 16 + mi;
            dst[c] = *(const bf16x8*)(w4t + (size_t)col * 1024 + k0 + q * 8);
        }
    };
    auto stepB = [&](int k0i, bf16x8 (&br)[4]) {
        int k0 = k0i * 32;
        int n = rg * 16 + mi;
        int r2 = 4 * n + (k0 >> 8);
        int kc = ((k0 & 255) >> 3) + q;
        bf16x8 a = *(const bf16x8*)(Ht + (r2 * 32 + (kc ^ (r2 & 31))) * 8);
        bf16x8 cur[4];
        #pragma unroll
        for (int c = 0; c < 4; ++c) cur[c] = br[c];
        if (k0i + 2 < 32) loadB((k0i + 2) * 32, br);
        #pragma unroll
        for (int c = 0; c < 4; ++c)
            acc2[c] = __builtin_amdgcn_mfma_f32_16x16x32_bf16(a, cur[c], acc2[c], 0, 0, 0);
    };
    loadB(0, b0); loadB(32, b1);
    for (int k0i = 0; k0i < 32; k0i += 2) {
        stepB(k0i, b0);
        stepB(k0i + 1, b1);
    }
    #pragma unroll
    for (int c = 0; c < 4; ++c) {
        int col = cgr * 64 + c * 16 + mi;
        float bv = b4[col];
        #pragma unroll
        for (int i = 0; i < 4; ++i) {
            int row = rg * 16 + q * 4 + i;          // 0..31
            t1[(size_t)(blockIdx.x * 32 + row) * 256 + col] =
                __float2bfloat16(acc2[c][i] + bv);
        }
    }
}

// ---------- D4: tailK — t2 + t3 + roots (32 blocks) --------------------------
// Phase A: t2 tile [128x256] = view(t1,[4096x1024]) @ W4 (PIPE) -> LDS Ht.
// Phase B: 32 rows -> Ht2, phase C: 8 roots -> out; both with register-B.
__global__ __launch_bounds__(512)
void tailK(const bf16* __restrict__ t1, const bf16* __restrict__ w4t,
           const float* __restrict__ b4, float* __restrict__ out) {
    constexpr int ASZ = 8192, STAGE = ASZ + 16384;
    __shared__ char smem[3 * STAGE];   // 72 KB; Ht overlays
    __shared__ bf16 Ht2[32 * 256];     // 16 KB
    bf16* Ht = (bf16*)smem;

    const int t = threadIdx.x, w = t >> 6, lane = t & 63;
    const int rg = w >> 2, cgr = w & 3, mi = lane & 15, q = lane >> 4;
    const int b = blockIdx.x;
    const int m0 = b * 128;

    auto stage = [&](int ke, int buf) {
        char* Asm = smem + buf * STAGE;
        char* Bsm = Asm + ASZ;
        int row = t >> 2;
        int kcd = (t & 3) ^ ((row >> 2) & 3);
        async_load16(t1 + (size_t)(m0 + row) * 1024 + ke + kcd * 8, Asm + w * 1024);
        #pragma unroll
        for (int i = 0; i < 2; ++i) {
            int s = i * 512 + t;
            int col = s >> 2;
            int kcd2 = (s & 3) ^ ((col >> 2) & 3);
            async_load16(w4t + (size_t)col * 1024 + ke + kcd2 * 8,
                         Bsm + i * 8192 + w * 1024);
        }
    };

    f32x4 acc[4][4] = {};
    stage(0, 0); stage(32, 1);
    for (int k0i = 0; k0i < 32; ++k0i) {
        if (k0i + 1 < 32)
            asm volatile("s_waitcnt vmcnt(3)\n\ts_barrier" ::: "memory");
        else
            asm volatile("s_waitcnt vmcnt(0)\n\ts_barrier" ::: "memory");
        if (k0i + 2 < 32) stage((k0i + 2) * 32, (k0i + 2) % 3);
        const bf16* As16 = (const bf16*)(smem + (k0i % 3) * STAGE);
        const bf16* Bs16 = (const bf16*)(smem + (k0i % 3) * STAGE + ASZ);
        bf16x8 af[4], bfr[4];
        #pragma unroll
        for (int r = 0; r < 4; ++r) {
            int row = rg * 64 + r * 16 + mi;
            int slot = row * 4 + (q ^ ((row >> 2) & 3));
            af[r] = *(const bf16x8*)(As16 + slot * 8);
        }
        #pragma unroll
        for (int c = 0; c < 4; ++c) {
            int col = cgr * 64 + c * 16 + mi;
            int slot = col * 4 + (q ^ ((col >> 2) & 3));
            bfr[c] = *(const bf16x8*)(Bs16 + slot * 8);
        }
        #pragma unroll
        for (int r = 0; r < 4; ++r)
            #pragma unroll
            for (int c = 0; c < 4; ++c)
                acc[r][c] = __builtin_amdgcn_mfma_f32_16x16x32_bf16(af[r], bfr[c], acc[r][c], 0, 0, 0);
    }
    __syncthreads();

    #pragma unroll
    for (int r = 0; r < 4; ++r) {
        int rowb = rg * 64 + r * 16 + q * 4;
        #pragma unroll
        for (int c = 0; c < 4; ++c) {
            int col = cgr * 64 + c * 16 + mi;
            float bv = b4[col];
            int chunk = col >> 3;
            #pragma unroll
            for (int i = 0; i < 4; ++i) {
                int row = rowb + i;
                Ht[(row * 32 + (chunk ^ (row & 31))) * 8 + (col & 7)] =
                    __float2bfloat16(acc[r][c][i] + bv);
            }
        }
    }
    __syncthreads();

    auto loadB = [&](int k0, bf16x8 (&dst)[4]) {
        #pragma unroll
        for (int c = 0; c < 4; ++c) {
            int col = cgr * 64 + c * 16 + mi;
            dst[c] = *(const bf16x8*)(w4t + (size_t)col * 1024 + k0 + q * 8);
        }
    };

    // phase B: 32 rows = view(Ht,[32x1024]) @ W4 + b4 -> Ht2
    {
        f32x4 acc2[4] = {};
        bf16x8 b0[4], b1[4];
        auto stepB = [&](int k0i, bf16x8 (&br)[4]) {
            int k0 = k0i * 32;
            int n = rg * 16 + mi;
            int r2 = 4 * n + (k0 >> 8);
            int kc = ((k0 & 255) >> 3) + q;
            bf16x8 a = *(const bf16x8*)(Ht + (r2 * 32 + (kc ^ (r2 & 31))) * 8);
            bf16x8 cur[4];
            #pragma unroll
            for (int c = 0; c < 4; ++c) cur[c] = br[c];
            if (k0i + 2 < 32) loadB((k0i + 2) * 32, br);
            #pragma unroll
            for (int c = 0; c < 4; ++c)
                acc2[c] = __builtin_amdgcn_mfma_f32_16x16x32_bf16(a, cur[c], acc2[c], 0, 0, 0);
        };
        loadB(0, b0); loadB(32, b1);
        for (int k0i = 0; k0i < 32; k0i += 2) {
            stepB(k0i, b0);
            stepB(k0i + 1, b1);
        }
        #pragma unroll
        for (int c = 0; c < 4; ++c) {
            int col = cgr * 64 + c * 16 + mi;
            float bv = b4[col];
            int chunk = col >> 3;
            #pragma unroll
            for (int i = 0; i < 4; ++i) {
                int row = rg * 16 + q * 4 + i;      // 0..31
                Ht2[(row * 32 + (chunk ^ (row & 31))) * 8 + (col & 7)] =
                    __float2bfloat16(acc2[c][i] + bv);
            }
        }
    }
    __syncthreads();

    // phase C: 8 roots = view(Ht2,[8x1024]) @ W4 + b4 -> fp32 out
    {
        f32x4 acc3[4] = {};
        bf16x8 b0[4], b1[4];
        auto stepC = [&](int k0i, bf16x8 (&br)[4]) {
            int k0 = k0i * 32;
            int r3 = (4 * mi + (k0 >> 8)) & 31;     // valid mi<8; rest unused
            int kc = ((k0 & 255) >> 3) + q;
            bf16x8 a = *(const bf16x8*)(Ht2 + (r3 * 32 + (kc ^ (r3 & 31))) * 8);
            bf16x8 cur[4];
            #pragma unroll
            for (int c = 0; c < 4; ++c) cur[c] = br[c];
            if (k0i + 2 < 32) loadB((k0i + 2) * 32, br);
            #pragma unroll
            for (int c = 0; c < 4; ++c)
                acc3[c] = __builtin_amdgcn_mfma_f32_16x16x32_bf16(a, cur[c], acc3[c], 0, 0, 0);
        };
        loadB(0, b0); loadB(32, b1);
        for (int k0i = 0; k0i < 32; k0i += 2) {
            stepC(k0i, b0);
            stepC(k0i + 1, b1);
        }
        if (rg == 0 && q < 2) {                     // rows 0..7 valid
            #pragma unroll
            for (int c = 0; c < 4; ++c) {
                int col = cgr * 64 + c * 16 + mi;
                float bv = b4[col];
                #pragma unroll
                for (int i = 0; i < 4; ++i)
                    out[(size_t)(b * 8 + q * 4 + i) * 256 + col] = acc3[c][i] + bv;
            }
        }
    }
}

extern "C" void kernel_launch(void* const* d_in, const int* in_sizes, int n_in,
                              void* d_out, int out_size, void* d_ws, size_t ws_size,
                              hipStream_t stream) {
    const int*   ids = (const int*)d_in[0];
    const float* emb = (const float*)d_in[1];
    const float* W1  = (const float*)d_in[2];
    const float* b1  = (const float*)d_in[3];
    const float* W2  = (const float*)d_in[4];
    const float* b2  = (const float*)d_in[5];
    (void)in_sizes; (void)n_in; (void)out_size; (void)ws_size;

    char* ws = (char*)d_ws;
    size_t off = 0;
    float* zbuf = (float*)(ws + off); off += 1024;
    float* b4   = (float*)(ws + off); off += 1024;
    bf16* w1t = (bf16*)(ws + off); off += (size_t)256 * KP1 * 2;     // 160 KB
    bf16* w2t = (bf16*)(ws + off); off += (size_t)256 * 512 * 2;     // 256 KB
    bf16* w2b = (bf16*)(ws + off); off += (size_t)512 * 256 * 2;     // 256 KB
    bf16* w4t = (bf16*)(ws + off); off += (size_t)256 * 1024 * 2;    // 512 KB
    bf16* proj = (bf16*)(ws + off); off += (size_t)MP * 256 * 2;     // 25.8 MB
    bf16* t1 = (bf16*)(ws + off); off += (size_t)16384 * 256 * 2;    // 8.4 MB
    (void)off;

    // D1: weight casts/transposes + b4 + zeros
    prep_w<<<1345, 256, 0, stream>>>(W1, W2, b2, w1t, w2t, w2b, b4, zbuf);

    // D2: W4T products || proj = emb@W1+b1
    combo<<<402, 512, 0, stream>>>(emb, w1t, b1, w2t, w2b, w4t, proj, zbuf);

    // D3: main — gather + levels 0-1 (phase A) + levels 2-3 (phase B) -> t1
    mainK<<<512, 512, 0, stream>>>(proj, ids, w4t, b4, t1);

    // D4: tail — levels 4-9: t2 tile + 32 rows + 8 roots per block
    tailK<<<32, 512, 0, stream>>>(t1, w4t, b4, (float*)d_out);
}

// Round 12
// 234.282 us; speedup vs baseline: 1.3484x; 1.3484x over previous
//
#include <hip/hip_runtime.h>
#include <hip/hip_bf16.h>
#include <stdint.h>

#define VOCAB 50257
#define WD 300
#define KP1 320              // word dim padded to mult of 32
#define MP 50432             // vocab rows padded: 394*128

using bf16 = __hip_bfloat16;
typedef __attribute__((ext_vector_type(4))) float f32x4;
typedef __attribute__((ext_vector_type(8))) short bf16x8;

// async global->LDS, 16B per lane; LDS dest = wave-uniform base + lane*16
__device__ __forceinline__ void async_load16(const void* g, void* l) {
    __builtin_amdgcn_global_load_lds(
        (const __attribute__((address_space(1))) uint32_t*)(uintptr_t)g,
        (__attribute__((address_space(3))) uint32_t*)l, 16, 0, 0);
}

// ---------- prep: w1t = W1^T bf16 [256x320]; w2t = W2^T bf16 [256x512];
//                  w2b = W2 cast bf16 [512x256]; b4 = b2@(A+B)+b2; zbuf zeros(256)
__global__ void prep_w(const float* __restrict__ W1, const float* __restrict__ W2,
                       const float* __restrict__ b2,
                       bf16* __restrict__ w1t, bf16* __restrict__ w2t,
                       bf16* __restrict__ w2b, float* __restrict__ b4,
                       float* __restrict__ zbuf) {
    if (blockIdx.x == 1344) {           // bias block: b4 = b2@(A+B) + b2
        __shared__ float b2s[256];
        int n = threadIdx.x;
        b2s[n] = b2[n];
        zbuf[n] = 0.0f;
        __syncthreads();
        float acc = b2s[n];
        #pragma unroll 8
        for (int k = 0; k < 256; ++k)
            acc += b2s[k] * (W2[k * 256 + n] + W2[(k + 256) * 256 + n]);
        b4[n] = acc;
        return;
    }
    int idx = blockIdx.x * 256 + threadIdx.x;
    if (idx < 256 * KP1) {                              // w1t
        int n = idx / KP1;
        int k = idx - n * KP1;
        w1t[idx] = __float2bfloat16(k < WD ? W1[k * 256 + n] : 0.0f);
    } else if (idx < 256 * KP1 + 131072) {              // w2t
        int j = idx - 256 * KP1;
        int n = j >> 9, k = j & 511;
        w2t[j] = __float2bfloat16(W2[k * 256 + n]);
    } else {                                            // w2b: plain cast
        int j = idx - 256 * KP1 - 131072;
        w2b[j] = __float2bfloat16(W2[j]);
    }
}

// ---------- unified 128-row x 256-col tile (8 waves: 2 rg x 4 cgr) -----------
// AMODE 0: A bf16, row stride As elems; 3-stage PIPE (verified R8/R10)
// AMODE 1: A row r = concat4(proj[ids4[m0+r]]), K = 1024; 3-stage PIPE (R10)
// AMODE 2: A fp32 rows stride WD (emb, clamped); single-stage 2-barrier (R10)
template <int AMODE, bool OUT_F32>
__device__ __forceinline__ void tile_gemm(
    char* smem, const void* Av, const int* ids,
    const bf16* BT, int Bstr, const float* bias,
    void* C, int Cs, int coff, int K, int As, int m0,
    const float* zbuf)
{
    constexpr int ASZ = (AMODE == 2) ? 16384 : 8192;
    constexpr int BSZ = 16384, STAGE = ASZ + BSZ;

    const int t = threadIdx.x, w = t >> 6, lane = t & 63;
    const int rg = w >> 2, cgr = w & 3, mi = lane & 15, q = lane >> 4;
    const bf16* Ab = (const bf16*)Av;

    int4 idq = {0, 0, 0, 0};
    if constexpr (AMODE == 1) idq = ((const int4*)ids)[m0 + (t >> 2)];

    auto stage = [&](int ke, int buf) {
        char* Asm = smem + buf * STAGE;
        char* Bsm = Asm + ASZ;
        if constexpr (AMODE == 2) {
            const float* A32 = (const float*)Av;
            #pragma unroll
            for (int i = 0; i < 2; ++i) {
                int s = i * 512 + t;
                int row = s >> 3;
                int kcd = (s & 7) ^ (row & 7);
                int k = ke + kcd * 4;
                int grow = m0 + row; if (grow >= VOCAB) grow = VOCAB - 1;
                const float* g = (k <= 296) ? (A32 + (size_t)grow * WD + k) : zbuf;
                async_load16(g, Asm + i * 8192 + w * 1024);
            }
        } else {
            int row = t >> 2;
            int kcd = (t & 3) ^ ((row >> 2) & 3);
            const bf16* g;
            if constexpr (AMODE == 1) {
                int sel = ke >> 8;
                int id = (sel & 2) ? ((sel & 1) ? idq.w : idq.z)
                                   : ((sel & 1) ? idq.y : idq.x);
                g = Ab + (size_t)id * 256 + (ke & 255) + kcd * 8;
            } else {
                g = Ab + (size_t)(m0 + row) * As + ke + kcd * 8;
            }
            async_load16(g, Asm + w * 1024);
        }
        #pragma unroll
        for (int i = 0; i < 2; ++i) {
            int s = i * 512 + t;
            int col = s >> 2;
            int kcd = (s & 3) ^ ((col >> 2) & 3);
            async_load16(BT + (size_t)col * Bstr + ke + kcd * 8,
                         Bsm + i * 8192 + w * 1024);
        }
    };

    f32x4 acc[4][4] = {};

    auto compute = [&](int buf) {
        const char* Asm = smem + buf * STAGE;
        const bf16* Bs16 = (const bf16*)(Asm + ASZ);
        bf16x8 af[4], bfr[4];
        if constexpr (AMODE == 2) {
            const float* As32 = (const float*)Asm;
            #pragma unroll
            for (int r = 0; r < 4; ++r) {
                int row = rg * 64 + r * 16 + mi;
                int sl = row * 8 + ((2 * q) ^ (row & 7));
                f32x4 lo = *(const f32x4*)(As32 + sl * 4);
                f32x4 hi = *(const f32x4*)(As32 + (sl ^ 1) * 4);
                union { bf16x8 v; bf16 hh[8]; } u;
                #pragma unroll
                for (int j = 0; j < 4; ++j) u.hh[j] = __float2bfloat16(lo[j]);
                #pragma unroll
                for (int j = 0; j < 4; ++j) u.hh[4 + j] = __float2bfloat16(hi[j]);
                af[r] = u.v;
            }
        } else {
            const bf16* As16 = (const bf16*)Asm;
            #pragma unroll
            for (int r = 0; r < 4; ++r) {
                int row = rg * 64 + r * 16 + mi;
                int slot = row * 4 + (q ^ ((row >> 2) & 3));
                af[r] = *(const bf16x8*)(As16 + slot * 8);
            }
        }
        #pragma unroll
        for (int c = 0; c < 4; ++c) {
            int col = cgr * 64 + c * 16 + mi;
            int slot = col * 4 + (q ^ ((col >> 2) & 3));
            bfr[c] = *(const bf16x8*)(Bs16 + slot * 8);
        }
        #pragma unroll
        for (int r = 0; r < 4; ++r)
            #pragma unroll
            for (int c = 0; c < 4; ++c)
                acc[r][c] = __builtin_amdgcn_mfma_f32_16x16x32_bf16(af[r], bfr[c], acc[r][c], 0, 0, 0);
    };

    const int S = K >> 5;
    if constexpr (AMODE == 2) {
        for (int k0 = 0; k0 < S; ++k0) {
            stage(k0 * 32, 0);
            __syncthreads();
            compute(0);
            __syncthreads();
        }
    } else {
        stage(0, 0);
        if (S > 1) stage(32, 1);
        for (int k0 = 0; k0 < S; ++k0) {
            if (k0 + 1 < S)
                asm volatile("s_waitcnt vmcnt(3)\n\ts_barrier" ::: "memory");
            else
                asm volatile("s_waitcnt vmcnt(0)\n\ts_barrier" ::: "memory");
            if (k0 + 2 < S) stage((k0 + 2) * 32, (k0 + 2) % 3);
            compute(k0 % 3);
        }
    }

    // epilogue: C/D layout col = lane&15, row = (lane>>4)*4 + i
    #pragma unroll
    for (int r = 0; r < 4; ++r) {
        int rowb = m0 + rg * 64 + r * 16 + q * 4;
        #pragma unroll
        for (int c = 0; c < 4; ++c) {
            int col = cgr * 64 + c * 16 + mi;
            float bv = bias[col];
            #pragma unroll
            for (int i = 0; i < 4; ++i) {
                float v = acc[r][c][i] + bv;
                size_t o = (size_t)(rowb + i) * Cs + coff + col;
                if (OUT_F32) ((float*)C)[o] = v;
                else         ((bf16*)C)[o] = __float2bfloat16(v);
            }
        }
    }
}

// ---------- D2: W4T (blocks 0..7) || proj (blocks 8..401) --------------------
__global__ __launch_bounds__(512)
void combo(const float* __restrict__ emb, const bf16* __restrict__ w1t,
           const float* __restrict__ b1, const bf16* __restrict__ w2t,
           const bf16* __restrict__ w2b, bf16* __restrict__ w4t,
           bf16* __restrict__ proj, const float* __restrict__ zbuf) {
    __shared__ char smem[73728];
    int blk = blockIdx.x;
    if (blk < 8) {
        int j = blk >> 1, s = blk & 1;
        tile_gemm<0, false>(smem, w2t + 256 * (j >> 1), nullptr,
                            w2b + 65536 * (j & 1), 256, zbuf,
                            w4t, 1024, 256 * j, 256, 512, s * 128, nullptr);
    } else {
        tile_gemm<2, false>(smem, emb, nullptr, w1t, KP1, b1,
                            proj, 256, 0, KP1, WD, (blk - 8) * 128, zbuf);
    }
}

// ---------- D3: main — h = concat4(proj[ids4]) @ W4 + b4 ---------------------
__global__ __launch_bounds__(512)
void mainK(const bf16* __restrict__ proj, const int* __restrict__ ids,
           const bf16* __restrict__ w4t, const float* __restrict__ b4,
           bf16* __restrict__ h) {
    __shared__ char smem[73728];
    tile_gemm<1, false>(smem, proj, ids, w4t, 1024, b4,
                        h, 256, 0, 1024, 256, blockIdx.x * 128, nullptr);
}

// ---------- D4: t1 = view(h,[16384x1024]) @ W4 + b4 --------------------------
__global__ __launch_bounds__(512)
void t1K(const bf16* __restrict__ h, const bf16* __restrict__ w4t,
         const float* __restrict__ b4, bf16* __restrict__ t1) {
    __shared__ char smem[73728];
    tile_gemm<0, false>(smem, h, nullptr, w4t, 1024, b4,
                        t1, 256, 0, 1024, 1024, blockIdx.x * 128, nullptr);
}

// ---------- D5: tail3 — t2 + t3 + roots (32 blocks) --------------------------
// Phase A: t2 tile [128x256] via verified PIPE -> LDS Ht (swizzled).
// Phases B/C: FAT 64-k B staging ([256x64] = 32KB x 2 buffers in smem) ->
// 16 rounds/phase instead of 32 (halves the serial-latency round count).
__global__ __launch_bounds__(512)
void tail3(const bf16* __restrict__ t1, const bf16* __restrict__ w4t,
           const float* __restrict__ b4, float* __restrict__ out) {
    constexpr int ASZ = 8192, BSZ = 16384, STAGE = ASZ + BSZ;
    __shared__ char smem[3 * STAGE];   // 72 KB (phase A pipeline; B/C fat bufs)
    __shared__ bf16 Ht[128 * 256];     // 64 KB
    __shared__ bf16 Ht2[32 * 256];     // 16 KB   (total 152 KB)

    const int t = threadIdx.x, w = t >> 6, lane = t & 63;
    const int rg = w >> 2, cgr = w & 3, mi = lane & 15, q = lane >> 4;
    const int b = blockIdx.x;
    const int m0 = b * 128;

    // ---- phase A: t2 tile [128 x 256] (verified PIPE) -> Ht ----
    {
        auto stageA = [&](int ke, int buf) {
            char* Asm = smem + buf * STAGE;
            char* Bsm = Asm + ASZ;
            int row = t >> 2;
            int kcd = (t & 3) ^ ((row >> 2) & 3);
            async_load16(t1 + (size_t)(m0 + row) * 1024 + ke + kcd * 8, Asm + w * 1024);
            #pragma unroll
            for (int i = 0; i < 2; ++i) {
                int s = i * 512 + t;
                int col = s >> 2;
                int kcd2 = (s & 3) ^ ((col >> 2) & 3);
                async_load16(w4t + (size_t)col * 1024 + ke + kcd2 * 8,
                             Bsm + i * 8192 + w * 1024);
            }
        };
        f32x4 acc[4][4] = {};
        stageA(0, 0); stageA(32, 1);
        for (int k0i = 0; k0i < 32; ++k0i) {
            if (k0i + 1 < 32)
                asm volatile("s_waitcnt vmcnt(3)\n\ts_barrier" ::: "memory");
            else
                asm volatile("s_waitcnt vmcnt(0)\n\ts_barrier" ::: "memory");
            if (k0i + 2 < 32) stageA((k0i + 2) * 32, (k0i + 2) % 3);
            const bf16* As16 = (const bf16*)(smem + (k0i % 3) * STAGE);
            const bf16* Bs16 = (const bf16*)(smem + (k0i % 3) * STAGE + ASZ);
            bf16x8 af[4], bfr[4];
            #pragma unroll
            for (int r = 0; r < 4; ++r) {
                int row = rg * 64 + r * 16 + mi;
                int slot = row * 4 + (q ^ ((row >> 2) & 3));
                af[r] = *(const bf16x8*)(As16 + slot * 8);
            }
            #pragma unroll
            for (int c = 0; c < 4; ++c) {
                int col = cgr * 64 + c * 16 + mi;
                int slot = col * 4 + (q ^ ((col >> 2) & 3));
                bfr[c] = *(const bf16x8*)(Bs16 + slot * 8);
            }
            #pragma unroll
            for (int r = 0; r < 4; ++r)
                #pragma unroll
                for (int c = 0; c < 4; ++c)
                    acc[r][c] = __builtin_amdgcn_mfma_f32_16x16x32_bf16(af[r], bfr[c], acc[r][c], 0, 0, 0);
        }
        // epilogue -> Ht: slot(row,col) = (row*32 + ((col>>3) ^ (row&31)))*8 + (col&7)
        #pragma unroll
        for (int r = 0; r < 4; ++r) {
            int rowb = rg * 64 + r * 16 + q * 4;
            #pragma unroll
            for (int c = 0; c < 4; ++c) {
                int col = cgr * 64 + c * 16 + mi;
                float bv = b4[col];
                int chunk = col >> 3;
                #pragma unroll
                for (int i = 0; i < 4; ++i) {
                    int row = rowb + i;
                    Ht[(row * 32 + (chunk ^ (row & 31))) * 8 + (col & 7)] =
                        __float2bfloat16(acc[r][c][i] + bv);
                }
            }
        }
    }
    __syncthreads();

    // fat B staging: [256 cols x 64 k] = 32 KB into smem + buf*32768
    auto stageF = [&](int ke, int buf) {
        char* Bb = smem + buf * 32768;
        #pragma unroll
        for (int sub = 0; sub < 2; ++sub)
            #pragma unroll
            for (int i = 0; i < 2; ++i) {
                int s = i * 512 + t;
                int col = s >> 2;
                int kcd = (s & 3) ^ ((col >> 2) & 3);
                async_load16(w4t + (size_t)col * 1024 + ke + sub * 32 + kcd * 8,
                             Bb + sub * 16384 + i * 8192 + w * 1024);
            }
    };

    // ---- phase B: 32 rows = view(Ht,[32x1024]) @ W4 + b4 -> Ht2 (16 rounds) ----
    {
        f32x4 acc2[4] = {};
        stageF(0, 0);
        for (int r = 0; r < 16; ++r) {
            if (r + 1 < 16) {
                stageF((r + 1) * 64, (r + 1) & 1);
                asm volatile("s_waitcnt vmcnt(4)\n\ts_barrier" ::: "memory");
            } else {
                asm volatile("s_waitcnt vmcnt(0)\n\ts_barrier" ::: "memory");
            }
            const bf16* Bb = (const bf16*)(smem + (r & 1) * 32768);
            #pragma unroll
            for (int sub = 0; sub < 2; ++sub) {
                int k0 = r * 64 + sub * 32;
                int n = rg * 16 + mi;
                int r2 = 4 * n + (k0 >> 8);
                int kc = ((k0 & 255) >> 3) + q;
                bf16x8 a = *(const bf16x8*)(Ht + (r2 * 32 + (kc ^ (r2 & 31))) * 8);
                #pragma unroll
                for (int c = 0; c < 4; ++c) {
                    int col = cgr * 64 + c * 16 + mi;
                    int slot = col * 4 + (q ^ ((col >> 2) & 3));
                    bf16x8 bb = *(const bf16x8*)(Bb + sub * 8192 + slot * 8);
                    acc2[c] = __builtin_amdgcn_mfma_f32_16x16x32_bf16(a, bb, acc2[c], 0, 0, 0);
                }
            }
            __syncthreads();
        }
        #pragma unroll
        for (int c = 0; c < 4; ++c) {
            int col = cgr * 64 + c * 16 + mi;
            float bv = b4[col];
            int chunk = col >> 3;
            #pragma unroll
            for (int i = 0; i < 4; ++i) {
                int row = rg * 16 + q * 4 + i;      // 0..31
                Ht2[(row * 32 + (chunk ^ (row & 31))) * 8 + (col & 7)] =
                    __float2bfloat16(acc2[c][i] + bv);
            }
        }
    }
    __syncthreads();

    // ---- phase C: 8 roots = view(Ht2,[8x1024]) @ W4 + b4 -> out (16 rounds) ----
    {
        f32x4 acc3[4] = {};
        stageF(0, 0);
        for (int r = 0; r < 16; ++r) {
            if (r + 1 < 16) {
                stageF((r + 1) * 64, (r + 1) & 1);
                asm volatile("s_waitcnt vmcnt(4)\n\ts_barrier" ::: "memory");
            } else {
                asm volatile("s_waitcnt vmcnt(0)\n\ts_barrier" ::: "memory");
            }
            const bf16* Bb = (const bf16*)(smem + (r & 1) * 32768);
            #pragma unroll
            for (int sub = 0; sub < 2; ++sub) {
                int k0 = r * 64 + sub * 32;
                int r3 = (4 * mi + (k0 >> 8)) & 31;     // valid mi<8; rest unused
                int kc = ((k0 & 255) >> 3) + q;
                bf16x8 a = *(const bf16x8*)(Ht2 + (r3 * 32 + (kc ^ (r3 & 31))) * 8);
                #pragma unroll
                for (int c = 0; c < 4; ++c) {
                    int col = cgr * 64 + c * 16 + mi;
                    int slot = col * 4 + (q ^ ((col >> 2) & 3));
                    bf16x8 bb = *(const bf16x8*)(Bb + sub * 8192 + slot * 8);
                    acc3[c] = __builtin_amdgcn_mfma_f32_16x16x32_bf16(a, bb, acc3[c], 0, 0, 0);
                }
            }
            __syncthreads();
        }
        if (rg == 0 && q < 2) {                         // rows 0..7 valid
            #pragma unroll
            for (int c = 0; c < 4; ++c) {
                int col = cgr * 64 + c * 16 + mi;
                float bv = b4[col];
                #pragma unroll
                for (int i = 0; i < 4; ++i)
                    out[(size_t)(b * 8 + q * 4 + i) * 256 + col] = acc3[c][i] + bv;
            }
        }
    }
}

extern "C" void kernel_launch(void* const* d_in, const int* in_sizes, int n_in,
                              void* d_out, int out_size, void* d_ws, size_t ws_size,
                              hipStream_t stream) {
    const int*   ids = (const int*)d_in[0];
    const float* emb = (const float*)d_in[1];
    const float* W1  = (const float*)d_in[2];
    const float* b1  = (const float*)d_in[3];
    const float* W2  = (const float*)d_in[4];
    const float* b2  = (const float*)d_in[5];
    (void)in_sizes; (void)n_in; (void)out_size; (void)ws_size;

    char* ws = (char*)d_ws;
    size_t off = 0;
    float* zbuf = (float*)(ws + off); off += 1024;
    float* b4   = (float*)(ws + off); off += 1024;
    bf16* w1t = (bf16*)(ws + off); off += (size_t)256 * KP1 * 2;     // 160 KB
    bf16* w2t = (bf16*)(ws + off); off += (size_t)256 * 512 * 2;     // 256 KB
    bf16* w2b = (bf16*)(ws + off); off += (size_t)512 * 256 * 2;     // 256 KB
    bf16* w4t = (bf16*)(ws + off); off += (size_t)256 * 1024 * 2;    // 512 KB
    bf16* proj = (bf16*)(ws + off); off += (size_t)MP * 256 * 2;     // 25.8 MB
    bf16* h  = (bf16*)(ws + off); off += (size_t)65536 * 256 * 2;    // 33.5 MB
    bf16* t1 = (bf16*)(ws + off); off += (size_t)16384 * 256 * 2;    // 8.4 MB
    (void)off;

    // D1: weight casts/transposes + b4 + zeros
    prep_w<<<1345, 256, 0, stream>>>(W1, W2, b2, w1t, w2t, w2b, b4, zbuf);

    // D2: W4T products (blocks 0..7) || proj = emb@W1+b1 (blocks 8..401)
    combo<<<402, 512, 0, stream>>>(emb, w1t, b1, w2t, w2b, w4t, proj, zbuf);

    // D3: main — leaves + levels 0-1 fused (PIPE)
    mainK<<<512, 512, 0, stream>>>(proj, ids, w4t, b4, h);

    // D4: t1 = levels 2-3 (view [16384x1024], PIPE)
    t1K<<<128, 512, 0, stream>>>(h, w4t, b4, t1);

    // D5: levels 4-9 block-local: t2 (PIPE) + fat-staged t3/roots, one dispatch
    tail3<<<32, 512, 0, stream>>>(t1, w4t, b4, (float*)d_out);
}